// Round 1
// baseline (429.832 us; speedup 1.0000x reference)
//
#include <hip/hip_runtime.h>

// TargetAttention: B=4096, L=200, D=64, fp32.
// R4: wave-per-row redesign. Evidence from R3: VGPR=60 proves the compiler
// sank the 26-deep load burst (needs 104 dest VGPRs) into per-load
// load->wait->consume, killing MLP; plus 8 barrier vmcnt(0) drains/block and
// ~2.7 blocks/CU resident -> 2.4 B/cyc/CU vs ~10 fair share (HBM 18%).
// Now: one 64-lane wave owns one row. Zero LDS, zero __syncthreads.
// K and V each stream through a rotating 12-deep float4 register window
// (12 KB in flight/wave), pinned with per-iteration sched_barrier(0x387)
// (VMEM may not cross; VALU/SALU/DS may). Softmax/reductions are pure wave
// shuffles. Grid 1024x256 -> 16 waves/CU, all resident, all independent.

#define B_ 4096
#define L_ 200
#define D_ 64
#define WIN 12

// sched_barrier mask: allow ALU|VALU|SALU|DS|DS_READ|DS_WRITE to cross,
// forbid VMEM/VMEM_READ/VMEM_WRITE -> loads stay where written.
#define PIN() __builtin_amdgcn_sched_barrier(0x387)

__global__ __launch_bounds__(256, 4) void ta_kernel(
    const float* __restrict__ tk,    // [B,D]
    const float* __restrict__ ik,    // [B,L,D]
    const float* __restrict__ iv,    // [B,L,D]
    const int*   __restrict__ mask,  // [B,L]
    const float* __restrict__ Wt,    // [D,D]
    const float* __restrict__ Wi,    // [D,D]
    const float* __restrict__ Wv,    // [D,D]
    float* __restrict__ out)         // [B,D]
{
  const int lane = threadIdx.x & 63;
  const int b    = blockIdx.x * 4 + (threadIdx.x >> 6);
  const int c    = lane & 15;   // float4 column chunk: cols [4c, 4c+4)
  const int rg   = lane >> 4;   // row-within-chunk 0..3

  // ---- phase 0: q[e=lane] = tk[b] @ Wt^T ; qt[d=lane] = q @ Wi ----
  // Weights are tiny (16 KB each) and L1/L2-hot after the first waves.
  const float4* tkb4 = (const float4*)(tk + (size_t)b * D_);
  const float4* Wt4  = (const float4*)Wt;
  float q = 0.f;
#pragma unroll
  for (int j = 0; j < 16; ++j) {
    float4 w = Wt4[lane * 16 + j];
    float4 x = tkb4[j];                       // uniform address: broadcast
    q += w.x * x.x + w.y * x.y + w.z * x.z + w.w * x.w;
  }
  float qt = 0.f;
#pragma unroll
  for (int e = 0; e < 64; ++e) {
    float qe = __shfl(q, e, 64);
    qt += qe * Wi[e * D_ + lane];             // coalesced over lane
  }
  // qc = qt[4c .. 4c+3] (this lane's column chunk of the query)
  float4 qc;
  qc.x = __shfl(qt, 4 * c + 0, 64);
  qc.y = __shfl(qt, 4 * c + 1, 64);
  qc.z = __shfl(qt, 4 * c + 2, 64);
  qc.w = __shfl(qt, 4 * c + 3, 64);

  // ---- mask bias for the rows this lane will hold: r = 64j + 4c + rg ----
  float bias[4];
#pragma unroll
  for (int j = 0; j < 4; ++j) {
    int r = 64 * j + 4 * c + rg;
    if (j < 3 || c < 2) {                     // r < 200
      int m = mask[(size_t)b * L_ + r];
      bias[j] = m ? 0.f : -1e8f;
    } else {
      bias[j] = 0.f;                          // slot never stored anyway
    }
  }

  const float4* ik4 = (const float4*)(ik + (size_t)b * (L_ * D_));
  const float4* iv4 = (const float4*)(iv + (size_t)b * (L_ * D_));

  // ---- K stream: 50 chunks of 4 rows, rotating WIN-deep pipeline ----
  float4 w_[WIN];
#pragma unroll
  for (int i = 0; i < WIN; ++i) w_[i] = ik4[i * 64 + lane];
  PIN();

  float s[4] = {-3e38f, -3e38f, -3e38f, -3e38f};
#pragma unroll
  for (int it = 0; it < 50; ++it) {
    float4 kv = w_[it % WIN];                 // waits vmcnt(WIN-1)
    if (it + WIN < 50) w_[it % WIN] = ik4[(it + WIN) * 64 + lane];
    float p = kv.x * qc.x + kv.y * qc.y + kv.z * qc.z + kv.w * qc.w;
    p += __shfl_xor(p, 8, 64);
    p += __shfl_xor(p, 4, 64);
    p += __shfl_xor(p, 2, 64);
    p += __shfl_xor(p, 1, 64);                // all 16 lanes of group rg hold row-sum
    // row it*4+rg is held by lane (rg, c==it&15) in slot j=it>>4
    if (c == (it & 15)) s[it >> 4] = p * 0.125f + bias[it >> 4];
    PIN();
  }

  // ---- issue first V window now so it flies under the softmax ----
#pragma unroll
  for (int i = 0; i < WIN; ++i) w_[i] = iv4[i * 64 + lane];
  PIN();

  // ---- softmax over 200 rows: pure wave shuffles, no barriers ----
  float mx = fmaxf(fmaxf(s[0], s[1]), fmaxf(s[2], s[3]));
#pragma unroll
  for (int off = 32; off >= 1; off >>= 1)
    mx = fmaxf(mx, __shfl_xor(mx, off, 64));
  float e_[4];
#pragma unroll
  for (int j = 0; j < 4; ++j) e_[j] = __expf(s[j] - mx);  // invalid slots -> 0
  float tt = e_[0] + e_[1] + e_[2] + e_[3];
#pragma unroll
  for (int off = 32; off >= 1; off >>= 1)
    tt += __shfl_xor(tt, off, 64);
  float rtot = 1.0f / tt;

  // ---- V stream: weighted accumulate, same rotating pipeline ----
  float4 acc = make_float4(0.f, 0.f, 0.f, 0.f);
#pragma unroll
  for (int it = 0; it < 50; ++it) {
    float4 vv = w_[it % WIN];
    if (it + WIN < 50) w_[it % WIN] = iv4[(it + WIN) * 64 + lane];
    // weight for row it*4+rg lives on lane (same rg, c = it&15), slot it>>4
    float wgt = __shfl(e_[it >> 4], (lane & 48) | (it & 15), 64);
    acc.x += wgt * vv.x;
    acc.y += wgt * vv.y;
    acc.z += wgt * vv.z;
    acc.w += wgt * vv.w;
    PIN();
  }

  // ---- normalize + reduce partial sums across rg (xor 16, 32) ----
  acc.x *= rtot; acc.y *= rtot; acc.z *= rtot; acc.w *= rtot;
  acc.x += __shfl_xor(acc.x, 16, 64); acc.x += __shfl_xor(acc.x, 32, 64);
  acc.y += __shfl_xor(acc.y, 16, 64); acc.y += __shfl_xor(acc.y, 32, 64);
  acc.z += __shfl_xor(acc.z, 16, 64); acc.z += __shfl_xor(acc.z, 32, 64);
  acc.w += __shfl_xor(acc.w, 16, 64); acc.w += __shfl_xor(acc.w, 32, 64);
  // now every lane with column-chunk c holds sv[4c..4c+3]

  // ---- epilogue: out[b, e=lane] = sv @ Wv^T (Wv L1-hot) ----
  const float4* Wv4 = (const float4*)Wv;
  float o = 0.f;
#pragma unroll
  for (int c2 = 0; c2 < 16; ++c2) {
    float sx = __shfl(acc.x, c2, 64);         // lane c2 has chunk c=c2
    float sy = __shfl(acc.y, c2, 64);
    float sz = __shfl(acc.z, c2, 64);
    float sw = __shfl(acc.w, c2, 64);
    float4 w4 = Wv4[lane * 16 + c2];
    o += sx * w4.x + sy * w4.y + sz * w4.z + sw * w4.w;
  }
  out[(size_t)b * D_ + lane] = o;
}

extern "C" void kernel_launch(void* const* d_in, const int* in_sizes, int n_in,
                              void* d_out, int out_size, void* d_ws, size_t ws_size,
                              hipStream_t stream) {
  const float* tk   = (const float*)d_in[0];  // target_key  [B,D]
  const float* ik   = (const float*)d_in[1];  // item_keys   [B,L,D]
  const float* iv   = (const float*)d_in[2];  // item_values [B,L,D]
  const int*   mask = (const int*)  d_in[3];  // mask        [B,L]
  const float* Wt   = (const float*)d_in[4];  // W_target    [D,D]
  const float* Wi   = (const float*)d_in[5];  // W_item      [D,D]
  const float* Wv   = (const float*)d_in[6];  // W_value     [D,D]
  float* out = (float*)d_out;                 // [B,D]

  ta_kernel<<<B_ / 4, 256, 0, stream>>>(tk, ik, iv, mask, Wt, Wi, Wv, out);
}

// Round 2
// 421.763 us; speedup vs baseline: 1.0191x; 1.0191x over previous
//
#include <hip/hip_runtime.h>

// TargetAttention: B=4096, L=200, D=64, fp32.
// R5: inline-asm streaming pipeline. R4 post-mortem: VGPR_Count=64 proved the
// regalloc collapsed the 12-deep float4 window (needs 48 live VGPRs) to ~3
// in flight (observed 223 cyc/iter = 700cyc latency / 3). sched_barrier alone
// cannot force liveness. Now every stream load is an inline-asm
// global_load_dwordx4 with a hand-counted s_waitcnt vmcnt(11) (AITER pattern:
// never drain to 0 mid-stream). V-prologue is issued as the K-tail's reissue
// so 12 loads stay in flight across the softmax; V-tail drains 11->0 with
// literal counted waits. One 64-lane wave per row, zero LDS, zero barriers.
// Grid 1024x256 = 4 waves/SIMD (grid-capped) -> 128 VGPR budget is free.

#define B_ 4096
#define L_ 200
#define D_ 64
#define WIN 12

#define SB0() __builtin_amdgcn_sched_barrier(0)
// Volatile asm load: forces a live "=v" dest (regalloc must keep the window),
// ordered against the waitcnt asms.
#define GLOAD(dst, ptr) \
  asm volatile("global_load_dwordx4 %0, %1, off" : "=v"(dst) : "v"(ptr))
// Counted wait + full scheduler fence (rule #18: VALU can hoist past an
// inline-asm waitcnt without it).
#define VWAITN(n) \
  do { asm volatile("s_waitcnt vmcnt(" #n ")" ::: "memory"); SB0(); } while (0)

__global__ __launch_bounds__(256, 4) void ta_kernel(
    const float* __restrict__ tk,    // [B,D]
    const float* __restrict__ ik,    // [B,L,D]
    const float* __restrict__ iv,    // [B,L,D]
    const int*   __restrict__ mask,  // [B,L]
    const float* __restrict__ Wt,    // [D,D]
    const float* __restrict__ Wi,    // [D,D]
    const float* __restrict__ Wv,    // [D,D]
    float* __restrict__ out)         // [B,D]
{
  const int lane = threadIdx.x & 63;
  const int b    = blockIdx.x * 4 + (threadIdx.x >> 6);
  const int c    = lane & 15;   // float4 column chunk: cols [4c, 4c+4)
  const int rg   = lane >> 4;   // row-within-chunk 0..3

  // ---- phase 0: q[e=lane] = tk[b] @ Wt^T ; qt[d=lane] = q @ Wi ----
  const float4* tkb4 = (const float4*)(tk + (size_t)b * D_);
  const float4* Wt4  = (const float4*)Wt;
  float q = 0.f;
#pragma unroll
  for (int j = 0; j < 16; ++j) {
    float4 w = Wt4[lane * 16 + j];
    float4 x = tkb4[j];                       // uniform address: broadcast
    q += w.x * x.x + w.y * x.y + w.z * x.z + w.w * x.w;
  }
  float qt = 0.f;
#pragma unroll
  for (int e = 0; e < 64; ++e)
    qt += __shfl(q, e, 64) * Wi[e * D_ + lane];   // coalesced over lane
  float4 qc;
  qc.x = __shfl(qt, 4 * c + 0, 64);
  qc.y = __shfl(qt, 4 * c + 1, 64);
  qc.z = __shfl(qt, 4 * c + 2, 64);
  qc.w = __shfl(qt, 4 * c + 3, 64);

  // ---- mask bias for the rows this lane will hold: r = 64j + 4c + rg ----
  // Consumed into registers BEFORE the stream so no compiler vmem op (and no
  // compiler-inserted vmcnt) lands inside the hand-counted region.
  float bias[4];
#pragma unroll
  for (int j = 0; j < 4; ++j) {
    int r = 64 * j + 4 * c + rg;
    bias[j] = 0.f;
    if (r < L_) bias[j] = mask[(size_t)b * L_ + r] ? 0.f : -1e8f;
  }

  const float4* ik4 = (const float4*)(ik + (size_t)b * (L_ * D_));
  const float4* iv4 = (const float4*)(iv + (size_t)b * (L_ * D_));

  float4 w_[WIN];
  float  s[4] = {-3e38f, -3e38f, -3e38f, -3e38f};

  // ---- establish vmcnt baseline: all compiler loads drained ----
  VWAITN(0);

  // ---- K prologue: fill the 12-deep window ----
#pragma unroll
  for (int i = 0; i < WIN; ++i) GLOAD(w_[i], ik4 + i * 64 + lane);

  // ---- K stream, steady state: wait vmcnt(11), consume oldest, reissue ----
#pragma unroll
  for (int it = 0; it < 38; ++it) {
    VWAITN(11);
    float4 kv = w_[it % WIN];
    GLOAD(w_[it % WIN], ik4 + (it + 12) * 64 + lane);
    float p = kv.x * qc.x + kv.y * qc.y + kv.z * qc.z + kv.w * qc.w;
    p += __shfl_xor(p, 8, 64);
    p += __shfl_xor(p, 4, 64);
    p += __shfl_xor(p, 2, 64);
    p += __shfl_xor(p, 1, 64);
    if (c == (it & 15)) s[it >> 4] = p * 0.125f + bias[it >> 4];
  }
  // ---- K tail doubles as V prologue: reissue slots with V chunks 0..11,
  //      keeping exactly 12 loads in flight (vmcnt(11) stays exact) ----
#pragma unroll
  for (int it = 38; it < 50; ++it) {
    VWAITN(11);
    float4 kv = w_[it % WIN];
    GLOAD(w_[it % WIN], iv4 + (it - 38) * 64 + lane);  // V chunk it-38 -> slot it%12
    float p = kv.x * qc.x + kv.y * qc.y + kv.z * qc.z + kv.w * qc.w;
    p += __shfl_xor(p, 8, 64);
    p += __shfl_xor(p, 4, 64);
    p += __shfl_xor(p, 2, 64);
    p += __shfl_xor(p, 1, 64);
    if (c == (it & 15)) s[it >> 4] = p * 0.125f + bias[it >> 4];
  }
  // V chunk j now lives in (or is in flight to) slot (j+2)%12.

  // ---- softmax over 200 rows: pure wave shuffles (V loads fly underneath) ----
  float mx = fmaxf(fmaxf(s[0], s[1]), fmaxf(s[2], s[3]));
#pragma unroll
  for (int off = 32; off >= 1; off >>= 1)
    mx = fmaxf(mx, __shfl_xor(mx, off, 64));
  float e_[4];
#pragma unroll
  for (int j = 0; j < 4; ++j) e_[j] = __expf(s[j] - mx);  // invalid slots -> 0
  float tt = e_[0] + e_[1] + e_[2] + e_[3];
#pragma unroll
  for (int off = 32; off >= 1; off >>= 1)
    tt += __shfl_xor(tt, off, 64);
  float rtot = 1.0f / tt;

  // ---- V stream: weighted accumulate, same rotating pipeline ----
  float4 acc = make_float4(0.f, 0.f, 0.f, 0.f);
#pragma unroll
  for (int it = 0; it < 38; ++it) {
    VWAITN(11);
    float4 vv = w_[(it + 2) % WIN];
    GLOAD(w_[(it + 2) % WIN], iv4 + (it + 12) * 64 + lane);
    float wgt = __shfl(e_[it >> 4], (lane & 48) | (it & 15), 64);
    acc.x += wgt * vv.x;
    acc.y += wgt * vv.y;
    acc.z += wgt * vv.z;
    acc.w += wgt * vv.w;
  }
  // ---- V tail: counted drain 11 -> 0, each iteration waits only its chunk ----
#define VTAIL(IT, N)                                                   \
  do {                                                                 \
    asm volatile("s_waitcnt vmcnt(" #N ")" ::: "memory"); SB0();       \
    float4 vv = w_[((IT) + 2) % WIN];                                  \
    float wgt = __shfl(e_[(IT) >> 4], (lane & 48) | ((IT) & 15), 64);  \
    acc.x += wgt * vv.x; acc.y += wgt * vv.y;                          \
    acc.z += wgt * vv.z; acc.w += wgt * vv.w;                          \
  } while (0)
  VTAIL(38, 11); VTAIL(39, 10); VTAIL(40, 9); VTAIL(41, 8);
  VTAIL(42, 7);  VTAIL(43, 6);  VTAIL(44, 5); VTAIL(45, 4);
  VTAIL(46, 3);  VTAIL(47, 2);  VTAIL(48, 1); VTAIL(49, 0);
#undef VTAIL

  // ---- normalize + reduce partial sums across rg (xor 16, 32) ----
  acc.x *= rtot; acc.y *= rtot; acc.z *= rtot; acc.w *= rtot;
  acc.x += __shfl_xor(acc.x, 16, 64); acc.x += __shfl_xor(acc.x, 32, 64);
  acc.y += __shfl_xor(acc.y, 16, 64); acc.y += __shfl_xor(acc.y, 32, 64);
  acc.z += __shfl_xor(acc.z, 16, 64); acc.z += __shfl_xor(acc.z, 32, 64);
  acc.w += __shfl_xor(acc.w, 16, 64); acc.w += __shfl_xor(acc.w, 32, 64);
  // every lane with column-chunk c now holds sv[4c..4c+3]

  // ---- epilogue: out[b, e=lane] = sv @ Wv^T (Wv L1-hot) ----
  const float4* Wv4 = (const float4*)Wv;
  float o = 0.f;
#pragma unroll
  for (int c2 = 0; c2 < 16; ++c2) {
    float sx = __shfl(acc.x, c2, 64);         // lane c2 holds chunk c=c2
    float sy = __shfl(acc.y, c2, 64);
    float sz = __shfl(acc.z, c2, 64);
    float sw = __shfl(acc.w, c2, 64);
    float4 w4 = Wv4[lane * 16 + c2];
    o += sx * w4.x + sy * w4.y + sz * w4.z + sw * w4.w;
  }
  out[(size_t)b * D_ + lane] = o;
}

extern "C" void kernel_launch(void* const* d_in, const int* in_sizes, int n_in,
                              void* d_out, int out_size, void* d_ws, size_t ws_size,
                              hipStream_t stream) {
  const float* tk   = (const float*)d_in[0];  // target_key  [B,D]
  const float* ik   = (const float*)d_in[1];  // item_keys   [B,L,D]
  const float* iv   = (const float*)d_in[2];  // item_values [B,L,D]
  const int*   mask = (const int*)  d_in[3];  // mask        [B,L]
  const float* Wt   = (const float*)d_in[4];  // W_target    [D,D]
  const float* Wi   = (const float*)d_in[5];  // W_item      [D,D]
  const float* Wv   = (const float*)d_in[6];  // W_value     [D,D]
  float* out = (float*)d_out;                 // [B,D]

  ta_kernel<<<B_ / 4, 256, 0, stream>>>(tk, ik, iv, mask, Wt, Wi, Wv, out);
}

// Round 3
// 420.835 us; speedup vs baseline: 1.0214x; 1.0022x over previous
//
#include <hip/hip_runtime.h>

// TargetAttention: B=4096, L=200, D=64, fp32.
// R6: named-register pipeline. R5 post-mortem: VGPR_Count=56 proved the
// float4 w_[12] array was scratch-demoted (rule #20: SROA runs before loop
// unroll; `it % WIN` is a runtime index at SROA time -> alloca -> scratch).
// Every slot became load->wait->scratch-store->scratch-load: serialized,
// ~3-deep MLP, same 140us as R3/R4. L3-hot replay dispatches (1 MB HBM)
// also took 140us -> runtime is memory-source-independent: pure latency
// serialization, 2x above the ~70us memory floor.
// Fix: 12 individually NAMED float4 vars + fully macro-unrolled straight-line
// pipeline (no loops around the asm, no indexing). asm "=v" on named SSA
// values cannot be demoted. Counted vmcnt(11) steady waits (AITER pattern),
// K-tail doubles as V-prologue, V-tail drains 11->0.
// Wave-per-row, zero LDS, zero barriers. Grid 1024x256 = 4 waves/SIMD;
// launch_bounds(256,4) -> 128 VGPR budget, need ~100.

#define B_ 4096
#define L_ 200
#define D_ 64

#define SB0() __builtin_amdgcn_sched_barrier(0)
#define GLOAD(dst, ptr) \
  asm volatile("global_load_dwordx4 %0, %1, off" : "=v"(dst) : "v"(ptr))
#define VWAITN(n) \
  do { asm volatile("s_waitcnt vmcnt(" #n ")" ::: "memory"); SB0(); } while (0)

__global__ __launch_bounds__(256, 4) void ta_kernel(
    const float* __restrict__ tk,    // [B,D]
    const float* __restrict__ ik,    // [B,L,D]
    const float* __restrict__ iv,    // [B,L,D]
    const int*   __restrict__ mask,  // [B,L]
    const float* __restrict__ Wt,    // [D,D]
    const float* __restrict__ Wi,    // [D,D]
    const float* __restrict__ Wv,    // [D,D]
    float* __restrict__ out)         // [B,D]
{
  const int lane = threadIdx.x & 63;
  const int b    = blockIdx.x * 4 + (threadIdx.x >> 6);
  const int c    = lane & 15;   // float4 column chunk: cols [4c, 4c+4)
  const int rg   = lane >> 4;   // row-within-chunk 0..3

  // ---- phase 0: q[e=lane] = tk[b] @ Wt^T ; qt[d=lane] = q @ Wi ----
  const float4* tkb4 = (const float4*)(tk + (size_t)b * D_);
  const float4* Wt4  = (const float4*)Wt;
  float q = 0.f;
#pragma unroll
  for (int j = 0; j < 16; ++j) {
    float4 w = Wt4[lane * 16 + j];
    float4 x = tkb4[j];                       // uniform address: broadcast
    q += w.x * x.x + w.y * x.y + w.z * x.z + w.w * x.w;
  }
  float qt = 0.f;
#pragma unroll
  for (int e = 0; e < 64; ++e)
    qt += __shfl(q, e, 64) * Wi[e * D_ + lane];   // coalesced over lane
  float4 qc;
  qc.x = __shfl(qt, 4 * c + 0, 64);
  qc.y = __shfl(qt, 4 * c + 1, 64);
  qc.z = __shfl(qt, 4 * c + 2, 64);
  qc.w = __shfl(qt, 4 * c + 3, 64);

  // ---- mask bias, consumed into registers BEFORE the counted region ----
  const int* mb = mask + (size_t)b * L_;
  float bias0 = mb[      4 * c + rg] ? 0.f : -1e8f;
  float bias1 = mb[ 64 + 4 * c + rg] ? 0.f : -1e8f;
  float bias2 = mb[128 + 4 * c + rg] ? 0.f : -1e8f;
  float bias3 = (c < 2) ? (mb[192 + 4 * c + rg] ? 0.f : -1e8f) : 0.f;

  const float4* ik4 = (const float4*)(ik + (size_t)b * (L_ * D_));
  const float4* iv4 = (const float4*)(iv + (size_t)b * (L_ * D_));

  // ---- the 12-deep window: NAMED variables, never indexed ----
  float4 w0, w1, w2, w3, w4, w5, w6, w7, w8, w9, w10, w11;
  float s0 = -3e38f, s1 = -3e38f, s2 = -3e38f, s3 = -3e38f;

  VWAITN(0);   // baseline: all compiler-issued loads drained

  // ---- K prologue: fill the window (12 in flight) ----
  GLOAD(w0,  ik4 +  0 * 64 + lane);  GLOAD(w1,  ik4 +  1 * 64 + lane);
  GLOAD(w2,  ik4 +  2 * 64 + lane);  GLOAD(w3,  ik4 +  3 * 64 + lane);
  GLOAD(w4,  ik4 +  4 * 64 + lane);  GLOAD(w5,  ik4 +  5 * 64 + lane);
  GLOAD(w6,  ik4 +  6 * 64 + lane);  GLOAD(w7,  ik4 +  7 * 64 + lane);
  GLOAD(w8,  ik4 +  8 * 64 + lane);  GLOAD(w9,  ik4 +  9 * 64 + lane);
  GLOAD(w10, ik4 + 10 * 64 + lane);  GLOAD(w11, ik4 + 11 * 64 + lane);

  // K steady step: consume slot, reissue K chunk IT+12 into it.
#define KS(IT, SLOT, J)                                                  \
  do {                                                                   \
    VWAITN(11);                                                          \
    float4 kv = w##SLOT;                                                 \
    GLOAD(w##SLOT, ik4 + ((IT) + 12) * 64 + lane);                       \
    float p = kv.x * qc.x + kv.y * qc.y + kv.z * qc.z + kv.w * qc.w;     \
    p += __shfl_xor(p, 8, 64); p += __shfl_xor(p, 4, 64);                \
    p += __shfl_xor(p, 2, 64); p += __shfl_xor(p, 1, 64);                \
    if (c == ((IT) & 15)) s##J = p * 0.125f + bias##J;                   \
  } while (0)
  // K tail step: consume slot, reissue V chunk VOFF into it (V prologue).
#define KT(IT, SLOT, J, VOFF)                                            \
  do {                                                                   \
    VWAITN(11);                                                          \
    float4 kv = w##SLOT;                                                 \
    GLOAD(w##SLOT, iv4 + (VOFF) * 64 + lane);                            \
    float p = kv.x * qc.x + kv.y * qc.y + kv.z * qc.z + kv.w * qc.w;     \
    p += __shfl_xor(p, 8, 64); p += __shfl_xor(p, 4, 64);                \
    p += __shfl_xor(p, 2, 64); p += __shfl_xor(p, 1, 64);                \
    if (c == ((IT) & 15)) s##J = p * 0.125f + bias##J;                   \
  } while (0)

  KS(0,0,0);   KS(1,1,0);   KS(2,2,0);   KS(3,3,0);
  KS(4,4,0);   KS(5,5,0);   KS(6,6,0);   KS(7,7,0);
  KS(8,8,0);   KS(9,9,0);   KS(10,10,0); KS(11,11,0);
  KS(12,0,0);  KS(13,1,0);  KS(14,2,0);  KS(15,3,0);
  KS(16,4,1);  KS(17,5,1);  KS(18,6,1);  KS(19,7,1);
  KS(20,8,1);  KS(21,9,1);  KS(22,10,1); KS(23,11,1);
  KS(24,0,1);  KS(25,1,1);  KS(26,2,1);  KS(27,3,1);
  KS(28,4,1);  KS(29,5,1);  KS(30,6,1);  KS(31,7,1);
  KS(32,8,2);  KS(33,9,2);  KS(34,10,2); KS(35,11,2);
  KS(36,0,2);  KS(37,1,2);
  KT(38,2,2,0);  KT(39,3,2,1);  KT(40,4,2,2);  KT(41,5,2,3);
  KT(42,6,2,4);  KT(43,7,2,5);  KT(44,8,2,6);  KT(45,9,2,7);
  KT(46,10,2,8); KT(47,11,2,9); KT(48,0,3,10); KT(49,1,3,11);
  // V chunk j now lives in (or is in flight to) slot (j+2)%12.

  // ---- softmax over 200 rows: pure wave shuffles (V loads in flight) ----
  float mx = fmaxf(fmaxf(s0, s1), fmaxf(s2, s3));
#pragma unroll
  for (int off = 32; off >= 1; off >>= 1)
    mx = fmaxf(mx, __shfl_xor(mx, off, 64));
  float e0 = __expf(s0 - mx);
  float e1 = __expf(s1 - mx);
  float e2 = __expf(s2 - mx);
  float e3 = __expf(s3 - mx);   // invalid slots (s=-3e38) -> 0
  float tt = e0 + e1 + e2 + e3;
#pragma unroll
  for (int off = 32; off >= 1; off >>= 1)
    tt += __shfl_xor(tt, off, 64);
  float rtot = 1.0f / tt;

  float4 acc = make_float4(0.f, 0.f, 0.f, 0.f);
  // V steady step: consume slot, reissue V chunk IT+12 into it.
#define VS(IT, SLOT, J)                                                  \
  do {                                                                   \
    VWAITN(11);                                                          \
    float4 vv = w##SLOT;                                                 \
    GLOAD(w##SLOT, iv4 + ((IT) + 12) * 64 + lane);                       \
    float wgt = __shfl(e##J, (lane & 48) | ((IT) & 15), 64);             \
    acc.x += wgt * vv.x; acc.y += wgt * vv.y;                            \
    acc.z += wgt * vv.z; acc.w += wgt * vv.w;                            \
  } while (0)
  // V tail step: counted drain, no reissue.
#define VT(IT, SLOT, J, N)                                               \
  do {                                                                   \
    VWAITN(N);                                                           \
    float4 vv = w##SLOT;                                                 \
    float wgt = __shfl(e##J, (lane & 48) | ((IT) & 15), 64);             \
    acc.x += wgt * vv.x; acc.y += wgt * vv.y;                            \
    acc.z += wgt * vv.z; acc.w += wgt * vv.w;                            \
  } while (0)

  VS(0,2,0);   VS(1,3,0);   VS(2,4,0);   VS(3,5,0);
  VS(4,6,0);   VS(5,7,0);   VS(6,8,0);   VS(7,9,0);
  VS(8,10,0);  VS(9,11,0);  VS(10,0,0);  VS(11,1,0);
  VS(12,2,0);  VS(13,3,0);  VS(14,4,0);  VS(15,5,0);
  VS(16,6,1);  VS(17,7,1);  VS(18,8,1);  VS(19,9,1);
  VS(20,10,1); VS(21,11,1); VS(22,0,1);  VS(23,1,1);
  VS(24,2,1);  VS(25,3,1);  VS(26,4,1);  VS(27,5,1);
  VS(28,6,1);  VS(29,7,1);  VS(30,8,1);  VS(31,9,1);
  VS(32,10,2); VS(33,11,2); VS(34,0,2);  VS(35,1,2);
  VS(36,2,2);  VS(37,3,2);
  VT(38,4,2,11); VT(39,5,2,10); VT(40,6,2,9); VT(41,7,2,8);
  VT(42,8,2,7);  VT(43,9,2,6);  VT(44,10,2,5); VT(45,11,2,4);
  VT(46,0,2,3);  VT(47,1,2,2);  VT(48,2,3,1);  VT(49,3,3,0);

  // ---- normalize + reduce partial sums across rg (xor 16, 32) ----
  acc.x *= rtot; acc.y *= rtot; acc.z *= rtot; acc.w *= rtot;
  acc.x += __shfl_xor(acc.x, 16, 64); acc.x += __shfl_xor(acc.x, 32, 64);
  acc.y += __shfl_xor(acc.y, 16, 64); acc.y += __shfl_xor(acc.y, 32, 64);
  acc.z += __shfl_xor(acc.z, 16, 64); acc.z += __shfl_xor(acc.z, 32, 64);
  acc.w += __shfl_xor(acc.w, 16, 64); acc.w += __shfl_xor(acc.w, 32, 64);
  // every lane with column-chunk c now holds sv[4c..4c+3]

  // ---- epilogue: out[b, e=lane] = sv @ Wv^T (Wv L1-hot) ----
  const float4* Wv4 = (const float4*)Wv;
  float o = 0.f;
#pragma unroll
  for (int c2 = 0; c2 < 16; ++c2) {
    float sx = __shfl(acc.x, c2, 64);         // lane c2 holds chunk c=c2
    float sy = __shfl(acc.y, c2, 64);
    float sz = __shfl(acc.z, c2, 64);
    float sw = __shfl(acc.w, c2, 64);
    float4 w4 = Wv4[lane * 16 + c2];
    o += sx * w4.x + sy * w4.y + sz * w4.z + sw * w4.w;
  }
  out[(size_t)b * D_ + lane] = o;
}

extern "C" void kernel_launch(void* const* d_in, const int* in_sizes, int n_in,
                              void* d_out, int out_size, void* d_ws, size_t ws_size,
                              hipStream_t stream) {
  const float* tk   = (const float*)d_in[0];  // target_key  [B,D]
  const float* ik   = (const float*)d_in[1];  // item_keys   [B,L,D]
  const float* iv   = (const float*)d_in[2];  // item_values [B,L,D]
  const int*   mask = (const int*)  d_in[3];  // mask        [B,L]
  const float* Wt   = (const float*)d_in[4];  // W_target    [D,D]
  const float* Wi   = (const float*)d_in[5];  // W_item      [D,D]
  const float* Wv   = (const float*)d_in[6];  // W_value     [D,D]
  float* out = (float*)d_out;                 // [B,D]

  ta_kernel<<<B_ / 4, 256, 0, stream>>>(tk, ik, iv, mask, Wt, Wi, Wv, out);
}